// Round 2
// baseline (1202.000 us; speedup 1.0000x reference)
//
#include <hip/hip_runtime.h>
#include <cstdint>
#include <cstddef>

// ---------------------------------------------------------------------------
// JointRetriveDeformHead — fp32 reference-accurate implementation (round 3)
// B=64, P=1024 pts, D=256, S=1024 sources, K=10, NPART=16, PL=32, NPAR=96,
// PSRC=512.
//
// Round 3 == round 2 resubmitted (round-1 bench was an infra failure, not a
// kernel verdict; audit found no hang/OOB/poison hazards):
//  - pointnet writes per-chunk maxima (g_part) with plain stores: removes
//    the hipMemsetAsync dispatch and the atomicMax tail.
//  - fc fused into topk (fc_topk): 5 dispatches -> 4, one less global
//    round-trip for enc.
//  - decoder processes (b,k) pairs in s-sorted order (tiny counting-sort
//    kernel): duplicate-s blocks become temporally adjacent so their
//    590 KB mat[s] slices hit L2/L3 instead of HBM (~25% of 377 MB).
// ---------------------------------------------------------------------------

#define NB    64
#define NPTS  1024
#define NSRC  1024
#define DIM   256
#define KRET  10
#define NPART 16
#define PL    32
#define NPAR  96
#define P3    1536   // 3*PSRC
#define NCHUNK 16

// ============================ PointNet (fused) =============================
// grid (16 chunks, 64 batch, 2 encoders), 256 threads.
// chunk = 64 points. layer1 -> h1 LDS -> layer2 -> h2 LDS -> layer3 + maxpool
// -> plain store of the per-chunk max into g_part[e][b][chunk][256].
__global__ __launch_bounds__(256) void pointnet_kernel(
    const float* __restrict__ noc,
    const float* __restrict__ te_W1, const float* __restrict__ te_b1,
    const float* __restrict__ te_W2, const float* __restrict__ te_b2,
    const float* __restrict__ te_W3, const float* __restrict__ te_b3,
    const float* __restrict__ re_W1, const float* __restrict__ re_b1,
    const float* __restrict__ re_W2, const float* __restrict__ re_b2,
    const float* __restrict__ re_W3, const float* __restrict__ re_b3,
    float* __restrict__ g_part)
{
  const int chunk = blockIdx.x;   // 0..15
  const int b     = blockIdx.y;   // 0..63
  const int e     = blockIdx.z;   // 0: te, 1: re

  const float* W1 = e ? re_W1 : te_W1;  const float* b1 = e ? re_b1 : te_b1;
  const float* W2 = e ? re_W2 : te_W2;  const float* b2 = e ? re_b2 : te_b2;
  const float* W3 = e ? re_W3 : te_W3;  const float* b3 = e ? re_b3 : te_b3;

  __shared__ __align__(16) float h1L[64][72];    // [point][64 dims + pad]
  __shared__ __align__(16) float h2L[64][132];   // [point][128 dims + pad]

  const int t = threadIdx.x;

  // ---- Phase A: layer1 (K=3 -> 64) ----
  {
    const int p = t & 63;
    const int w = t >> 6;           // wave id -> k group
    const float p0 = noc[(b*3 + 0)*NPTS + chunk*64 + p];
    const float p1 = noc[(b*3 + 1)*NPTS + chunk*64 + p];
    const float p2 = noc[(b*3 + 2)*NPTS + chunk*64 + p];
    #pragma unroll
    for (int kk = 0; kk < 16; ++kk) {
      const int k = w*16 + kk;
      float v = b1[k] + p0*W1[0*64 + k] + p1*W1[1*64 + k] + p2*W1[2*64 + k];
      h1L[p][k] = fmaxf(v, 0.f);
    }
  }
  __syncthreads();

  // ---- Phase B: layer2 (64x128, K=64), micro-tile 8p x 4j ----
  {
    const int tp = t >> 5;   // 0..7
    const int tj = t & 31;   // 0..31
    float acc[8][4];
    #pragma unroll
    for (int pp = 0; pp < 8; ++pp)
      #pragma unroll
      for (int jj = 0; jj < 4; ++jj) acc[pp][jj] = 0.f;

    for (int k = 0; k < 64; k += 4) {
      float4 a[8];
      #pragma unroll
      for (int pp = 0; pp < 8; ++pp)
        a[pp] = *(const float4*)&h1L[tp*8 + pp][k];
      float4 w[4];
      #pragma unroll
      for (int kk = 0; kk < 4; ++kk)
        w[kk] = *(const float4*)&W2[(k + kk)*128 + tj*4];
      #pragma unroll
      for (int pp = 0; pp < 8; ++pp) {
        const float* av = (const float*)&a[pp];
        #pragma unroll
        for (int kk = 0; kk < 4; ++kk) {
          const float* wv = (const float*)&w[kk];
          #pragma unroll
          for (int jj = 0; jj < 4; ++jj)
            acc[pp][jj] += av[kk] * wv[jj];
        }
      }
    }
    float4 bv = *(const float4*)&b2[tj*4];
    const float* bvv = (const float*)&bv;
    #pragma unroll
    for (int pp = 0; pp < 8; ++pp) {
      float4 r;
      float* rv = (float*)&r;
      #pragma unroll
      for (int jj = 0; jj < 4; ++jj)
        rv[jj] = fmaxf(acc[pp][jj] + bvv[jj], 0.f);
      *(float4*)&h2L[tp*8 + pp][tj*4] = r;
    }
  }
  __syncthreads();

  // ---- Phase C: layer3 (64x256, K=128) + maxpool, micro-tile 8p x 8j ----
  {
    const int tp = t >> 5;   // 0..7 -> points 8tp..
    const int tj = t & 31;   // 0..31 -> j 8tj..
    float acc[8][8];
    #pragma unroll
    for (int pp = 0; pp < 8; ++pp)
      #pragma unroll
      for (int jj = 0; jj < 8; ++jj) acc[pp][jj] = 0.f;

    for (int k = 0; k < 128; k += 4) {
      float4 a[8];
      #pragma unroll
      for (int pp = 0; pp < 8; ++pp)
        a[pp] = *(const float4*)&h2L[tp*8 + pp][k];
      float4 w0[4], w1[4];
      #pragma unroll
      for (int kk = 0; kk < 4; ++kk) {
        w0[kk] = *(const float4*)&W3[(k + kk)*256 + tj*8];
        w1[kk] = *(const float4*)&W3[(k + kk)*256 + tj*8 + 4];
      }
      #pragma unroll
      for (int pp = 0; pp < 8; ++pp) {
        const float* av = (const float*)&a[pp];
        #pragma unroll
        for (int kk = 0; kk < 4; ++kk) {
          const float* wa = (const float*)&w0[kk];
          const float* wb = (const float*)&w1[kk];
          #pragma unroll
          for (int jj = 0; jj < 4; ++jj) {
            acc[pp][jj]     += av[kk] * wa[jj];
            acc[pp][jj + 4] += av[kk] * wb[jj];
          }
        }
      }
    }

    // bias + relu + max over the 8 points of this thread
    float bb[8];
    {
      float4 b3a = *(const float4*)&b3[tj*8];
      float4 b3b = *(const float4*)&b3[tj*8 + 4];
      const float* xa = (const float*)&b3a;
      const float* xb = (const float*)&b3b;
      #pragma unroll
      for (int jj = 0; jj < 4; ++jj) { bb[jj] = xa[jj]; bb[jj+4] = xb[jj]; }
    }
    float m[8];
    #pragma unroll
    for (int jj = 0; jj < 8; ++jj) {
      float mx = 0.f;
      #pragma unroll
      for (int pp = 0; pp < 8; ++pp)
        mx = fmaxf(mx, fmaxf(acc[pp][jj] + bb[jj], 0.f));
      m[jj] = mx;
    }

    // cross-thread max: redL[8 tp][256 j] reuses h1L storage (safe: h1L dead
    // after phase-B barrier, nothing reads it in phase C).
    float* redL = &h1L[0][0];
    {
      float4 r0, r1;
      float* a0 = (float*)&r0; float* a1 = (float*)&r1;
      #pragma unroll
      for (int jj = 0; jj < 4; ++jj) { a0[jj] = m[jj]; a1[jj] = m[jj+4]; }
      *(float4*)&redL[tp*260 + tj*8]     = r0;
      *(float4*)&redL[tp*260 + tj*8 + 4] = r1;
    }
    __syncthreads();
    {
      float mx = redL[t];
      #pragma unroll
      for (int q = 1; q < 8; ++q) mx = fmaxf(mx, redL[q*260 + t]);
      // plain store of the per-chunk max (no atomics, no memset needed)
      g_part[(((e*NB + b)*NCHUNK) + chunk)*DIM + t] = mx;
    }
  }
}

// ===================== fused final-FC + distances + top-K ==================
// one block per batch b. Reduces the 16 per-chunk maxima, runs both final
// FCs (te -> enc_te global for the decoder, re -> LDS for retrieval),
// then the variance-weighted distances + top-10 selection.
__global__ __launch_bounds__(256) void fc_topk_kernel(
    const float* __restrict__ g_part,       // [2][64][16][256]
    const float* __restrict__ te_Wf, const float* __restrict__ te_bf,
    const float* __restrict__ re_Wf, const float* __restrict__ re_bf,
    const float* __restrict__ var,          // src_variances [S][256]
    const float* __restrict__ codes,        // ret_src_codes [S][256]
    float* __restrict__ enc_te,             // [64][256]
    int* __restrict__ idxW)                 // [64][10]
{
  const int b = blockIdx.x;
  const int t = threadIdx.x;
  __shared__ __align__(16) float gteL[256];
  __shared__ __align__(16) float greL[256];
  __shared__ __align__(16) float retL[256];
  __shared__ __align__(16) float dL[1024];
  __shared__ float rV[256];
  __shared__ int   rI[256];

  // ---- reduce the 16 chunk maxima (exact max, order-free) ----
  float gte = 0.f, gre = 0.f;
  #pragma unroll
  for (int c = 0; c < NCHUNK; ++c) {
    gte = fmaxf(gte, g_part[((0*NB + b)*NCHUNK + c)*DIM + t]);
    gre = fmaxf(gre, g_part[((1*NB + b)*NCHUNK + c)*DIM + t]);
  }
  gteL[t] = gte;
  greL[t] = gre;
  __syncthreads();

  // ---- final FC, te (same accumulation order as round-1 fc_kernel) ----
  {
    float acc = te_bf[t];
    #pragma unroll 4
    for (int i = 0; i < 256; ++i)
      acc += gteL[i] * te_Wf[i*256 + t];
    enc_te[b*DIM + t] = acc;
  }
  // ---- final FC, re (feeds retrieval distances, stays in LDS) ----
  {
    float acc = re_bf[t];
    #pragma unroll 4
    for (int i = 0; i < 256; ++i)
      acc += greL[i] * re_Wf[i*256 + t];
    retL[t] = acc;
  }
  __syncthreads();

  // ---- variance-weighted squared distances to all 1024 sources ----
  for (int s0 = 0; s0 < 4; ++s0) {
    const int s = s0*256 + t;
    const float4* vp = (const float4*)&var[s*DIM];
    const float4* cp = (const float4*)&codes[s*DIM];
    float acc = 0.f;
    #pragma unroll 4
    for (int c = 0; c < 64; ++c) {
      float4 v  = vp[c];
      float4 cd = cp[c];
      float4 r  = *(const float4*)&retL[c*4];
      float d0 = r.x - cd.x, d1 = r.y - cd.y, d2 = r.z - cd.z, d3 = r.w - cd.w;
      acc += v.x*d0*d0 + v.y*d1*d1 + v.z*d2*d2 + v.w*d3*d3;
    }
    dL[s] = acc;
  }
  __syncthreads();

  // ---- top-10 selection (identical tie-breaking to round 1) ----
  for (int kk = 0; kk < KRET; ++kk) {
    float bv = dL[t]; int bi = t;
    #pragma unroll
    for (int s0 = 1; s0 < 4; ++s0) {
      const int s = s0*256 + t;
      const float v = dL[s];
      if (v < bv) { bv = v; bi = s; }
    }
    rV[t] = bv; rI[t] = bi;
    __syncthreads();
    for (int off = 128; off > 0; off >>= 1) {
      if (t < off) {
        const float v = rV[t + off]; const int i2 = rI[t + off];
        if (v < rV[t] || (v == rV[t] && i2 < rI[t])) { rV[t] = v; rI[t] = i2; }
      }
      __syncthreads();
    }
    if (t == 0) { idxW[b*KRET + kk] = rI[0]; dL[rI[0]] = 3.4e38f; }
    __syncthreads();
  }
}

// ==================== order (b,k) pairs by source id =======================
// Counting sort of the 640 flat (b,k) indices by their source s, so decoder
// blocks with the same mat[s] slice run temporally adjacent (L2/L3 hits on
// the ~25% duplicate picks). Any permutation is semantically correct; the
// sort only affects locality.
__global__ __launch_bounds__(256) void order_kernel(
    const int* __restrict__ idxW,           // [64][10] flat
    int* __restrict__ order)                // [640]
{
  __shared__ int counts[NSRC];
  __shared__ int bsum[256];
  const int t = threadIdx.x;

  #pragma unroll
  for (int j = 0; j < 4; ++j) counts[t*4 + j] = 0;
  __syncthreads();

  for (int i = t; i < NB*KRET; i += 256)
    atomicAdd(&counts[idxW[i]], 1);
  __syncthreads();

  const int c0 = counts[t*4 + 0], c1 = counts[t*4 + 1];
  const int c2 = counts[t*4 + 2], c3 = counts[t*4 + 3];
  const int local = c0 + c1 + c2 + c3;

  // inclusive Hillis-Steele scan over the 256 per-thread partials
  bsum[t] = local;
  __syncthreads();
  for (int off = 1; off < 256; off <<= 1) {
    const int v = (t >= off) ? bsum[t - off] : 0;
    __syncthreads();
    bsum[t] += v;
    __syncthreads();
  }
  int run = bsum[t] - local;   // exclusive prefix for this thread's 4 bins
  counts[t*4 + 0] = run; run += c0;
  counts[t*4 + 1] = run; run += c1;
  counts[t*4 + 2] = run; run += c2;
  counts[t*4 + 3] = run;
  __syncthreads();

  for (int i = t; i < NB*KRET; i += 256) {
    const int s = idxW[i];
    const int pos = atomicAdd(&counts[s], 1);
    order[pos] = i;
  }
}

// ============================ decoder (fused) ==============================
// one block per sorted (b,k) pair. 640 blocks, 256 threads.
__global__ __launch_bounds__(256) void decoder_kernel(
    const float* __restrict__ enc_te,       // [64][256]
    const int*   __restrict__ idxW,
    const int*   __restrict__ order,        // s-sorted pair permutation
    const float* __restrict__ src_codes,    // [S][256]
    const float* __restrict__ part_latent,  // [S][16][32]
    const float* __restrict__ dW1, const float* __restrict__ db1,  // [544][256]
    const float* __restrict__ dW2, const float* __restrict__ db2,  // [256][256]
    const float* __restrict__ dW3, const float* __restrict__ db3,  // [256][6]
    const float* __restrict__ def_param,    // [S][96]
    const float* __restrict__ proj,         // [S][96][96]
    const float* __restrict__ mat,          // [S][1536][96]
    float* __restrict__ out)                // [64][10][1536]
{
  const int pair = order[blockIdx.x];
  const int b = pair / KRET, k = pair % KRET;
  const int t = threadIdx.x;

  __shared__ __align__(16) float shx[512];            // [tgt(256) | src(256)]
  __shared__ __align__(16) float partsL[NPART*PL];    // [16][32]
  __shared__ __align__(16) float h1L[NPART][260];
  __shared__ __align__(16) float h2L[NPART][260];
  __shared__ __align__(16) float rawL[NPAR];
  __shared__ __align__(16) float paramsL[NPAR];

  const int s = idxW[b*KRET + k];

  shx[t]        = enc_te[b*DIM + t];              // tgt (te encoder)
  shx[256 + t]  = src_codes[s*DIM + t];
  partsL[t]       = part_latent[s*512 + t];
  partsL[256 + t] = part_latent[s*512 + 256 + t];
  __syncthreads();

  // ---- layer1: shared 512-dim part once, + per-part 32-dim tail ----
  {
    float acc = 0.f;
    for (int i4 = 0; i4 < 128; ++i4) {
      float4 xv = *(const float4*)&shx[i4*4];
      acc += xv.x * dW1[(i4*4 + 0)*256 + t];
      acc += xv.y * dW1[(i4*4 + 1)*256 + t];
      acc += xv.z * dW1[(i4*4 + 2)*256 + t];
      acc += xv.w * dW1[(i4*4 + 3)*256 + t];
    }
    float wreg[32];
    #pragma unroll
    for (int i = 0; i < 32; ++i) wreg[i] = dW1[(512 + i)*256 + t];
    const float base = acc + db1[t];
    #pragma unroll
    for (int n = 0; n < NPART; ++n) {
      float v = base;
      #pragma unroll
      for (int i = 0; i < 32; ++i)
        v += partsL[n*32 + i] * wreg[i];
      h1L[n][t] = fmaxf(v, 0.f);
    }
  }
  __syncthreads();

  // ---- layer2: 16x256 @ 256x256.  thread (n = t>>4, jt = t&15), acc[16] ----
  {
    const int n  = t >> 4;
    const int jt = t & 15;
    float acc[16];
    #pragma unroll
    for (int jj = 0; jj < 16; ++jj) acc[jj] = 0.f;
    for (int c = 0; c < 256; ++c) {
      const float hv = h1L[n][c];
      const float4* wr = (const float4*)&dW2[c*256 + jt*16];
      const float4 w0 = wr[0], w1 = wr[1], w2 = wr[2], w3 = wr[3];
      acc[0]  += hv*w0.x; acc[1]  += hv*w0.y; acc[2]  += hv*w0.z; acc[3]  += hv*w0.w;
      acc[4]  += hv*w1.x; acc[5]  += hv*w1.y; acc[6]  += hv*w1.z; acc[7]  += hv*w1.w;
      acc[8]  += hv*w2.x; acc[9]  += hv*w2.y; acc[10] += hv*w2.z; acc[11] += hv*w2.w;
      acc[12] += hv*w3.x; acc[13] += hv*w3.y; acc[14] += hv*w3.z; acc[15] += hv*w3.w;
    }
    #pragma unroll
    for (int q = 0; q < 4; ++q) {
      float4 r;
      float* rv = (float*)&r;
      #pragma unroll
      for (int u = 0; u < 4; ++u) {
        const int j = jt*16 + q*4 + u;
        rv[u] = fmaxf(acc[q*4 + u] + db2[j], 0.f);
      }
      *(float4*)&h2L[n][jt*16 + q*4] = r;
    }
  }
  __syncthreads();

  // ---- layer3: 16x256 @ 256x6 -> raw[96] (no relu) ----
  if (t < 96) {
    const int n = t / 6, r = t % 6;
    float acc = db3[r];
    #pragma unroll 4
    for (int c = 0; c < 256; ++c)
      acc += h2L[n][c] * dW3[c*6 + r];
    rawL[t] = acc;   // t == n*6 + r
  }
  __syncthreads();

  // ---- params = proj[s] @ raw + def_param[s] ----
  if (t < NPAR) {
    float acc = def_param[s*NPAR + t];
    const float4* pr = (const float4*)&proj[((size_t)s*NPAR + t)*NPAR];
    #pragma unroll
    for (int j4 = 0; j4 < 24; ++j4) {
      float4 p = pr[j4];
      float4 r = *(const float4*)&rawL[j4*4];
      acc += p.x*r.x + p.y*r.y + p.z*r.z + p.w*r.w;
    }
    paramsL[t] = acc;
  }
  __syncthreads();

  // ---- pts_def = mat[s] @ params  (memory-bound gather) ----
  for (int p = t; p < P3; p += 256) {
    const float4* mr = (const float4*)&mat[(size_t)s*P3*NPAR + (size_t)p*NPAR];
    float acc = 0.f;
    #pragma unroll
    for (int j4 = 0; j4 < 24; ++j4) {
      float4 m = mr[j4];
      float4 pa = *(const float4*)&paramsL[j4*4];
      acc += m.x*pa.x + m.y*pa.y + m.z*pa.z + m.w*pa.w;
    }
    out[((size_t)(b*KRET + k))*P3 + p] = acc;
  }
}

// ============================ launch =======================================
extern "C" void kernel_launch(void* const* d_in, const int* in_sizes, int n_in,
                              void* d_out, int out_size, void* d_ws, size_t ws_size,
                              hipStream_t stream) {
  const float* noc   = (const float*)d_in[0];
  const float* te_W1 = (const float*)d_in[1];
  const float* te_b1 = (const float*)d_in[2];
  const float* te_W2 = (const float*)d_in[3];
  const float* te_b2 = (const float*)d_in[4];
  const float* te_W3 = (const float*)d_in[5];
  const float* te_b3 = (const float*)d_in[6];
  const float* te_Wf = (const float*)d_in[7];
  const float* te_bf = (const float*)d_in[8];
  const float* re_W1 = (const float*)d_in[9];
  const float* re_b1 = (const float*)d_in[10];
  const float* re_W2 = (const float*)d_in[11];
  const float* re_b2 = (const float*)d_in[12];
  const float* re_W3 = (const float*)d_in[13];
  const float* re_b3 = (const float*)d_in[14];
  const float* re_Wf = (const float*)d_in[15];
  const float* re_bf = (const float*)d_in[16];
  const float* dec_W1 = (const float*)d_in[17];
  const float* dec_b1 = (const float*)d_in[18];
  const float* dec_W2 = (const float*)d_in[19];
  const float* dec_b2 = (const float*)d_in[20];
  const float* dec_W3 = (const float*)d_in[21];
  const float* dec_b3 = (const float*)d_in[22];
  const float* ret_src_codes = (const float*)d_in[23];
  const float* src_codes     = (const float*)d_in[24];
  const float* src_variances = (const float*)d_in[25];
  const float* part_latent   = (const float*)d_in[26];
  const float* def_param     = (const float*)d_in[27];
  const float* proj_mat      = (const float*)d_in[28];
  const float* mat           = (const float*)d_in[29];

  float* g_part = (float*)d_ws;                    // [2][64][16][256] = 2 MB
  float* enc_te = g_part + 2*NB*NCHUNK*DIM;        // [64][256]
  int*   idxW   = (int*)(enc_te + NB*DIM);         // [64][10]
  int*   order  = idxW + NB*KRET;                  // [640]

  pointnet_kernel<<<dim3(NCHUNK, NB, 2), 256, 0, stream>>>(
      noc, te_W1, te_b1, te_W2, te_b2, te_W3, te_b3,
      re_W1, re_b1, re_W2, re_b2, re_W3, re_b3, g_part);

  fc_topk_kernel<<<NB, 256, 0, stream>>>(
      g_part, te_Wf, te_bf, re_Wf, re_bf,
      src_variances, ret_src_codes, enc_te, idxW);

  order_kernel<<<1, 256, 0, stream>>>(idxW, order);

  decoder_kernel<<<640, 256, 0, stream>>>(
      enc_te, idxW, order, src_codes, part_latent,
      dec_W1, dec_b1, dec_W2, dec_b2, dec_W3, dec_b3,
      def_param, proj_mat, mat, (float*)d_out);
}